// Round 4
// baseline (346.970 us; speedup 1.0000x reference)
//
#include <hip/hip_runtime.h>

namespace {

typedef __attribute__((ext_vector_type(8))) short short8;
typedef __attribute__((ext_vector_type(4))) float f32x4;

constexpr int Hh = 32, Ss = 4096, HP = 64, HN = 64, NCH = 64;
constexpr int ST = 68;  // bf16 row stride: 136B = 17*8 (8B-aligned rows, 34 dw == 2 mod 32)

__device__ inline unsigned short f2bf(float f) {
  unsigned u = __float_as_uint(f);
  u += 0x7FFFu + ((u >> 16) & 1u);  // RNE
  return (unsigned short)(u >> 16);
}

__device__ inline short8 frag(const unsigned short* p) {
  union { short8 s; uint2 u[2]; } r;
  r.u[0] = *(const uint2*)p;        // rows are 8B-aligned, not 16B: two b64 loads
  r.u[1] = *(const uint2*)(p + 4);
  return r.s;
}

__device__ inline uint2 cvt4(float4 v) {
  uint2 o; unsigned short* s = (unsigned short*)&o;
  s[0] = f2bf(v.x); s[1] = f2bf(v.y); s[2] = f2bf(v.z); s[3] = f2bf(v.w);
  return o;
}

__device__ inline uint2 sxor8(uint2 v) {
  uint2 o;
  o.x = (unsigned)__shfl_xor((int)v.x, 8);
  o.y = (unsigned)__shfl_xor((int)v.y, 8);
  return o;
}

// Block = (batch, head, p-half). 1024 threads (16 waves, 4/SIMD). Waves 0-7:
// G + Y; waves 8-15: state update (fp32 master in regs) + B/C staging.
// 2 barriers/chunk. exp only in the A-scan. iel[l] is folded into BOTH staged
// B buffers: Bs rows are read as the s-index in phase A (needs iel[s]); BT is
// summed over l in phase C (needs iel[l]).
__global__ __launch_bounds__(1024, 4)
void ssd4(const float* __restrict__ Xg0, const float* __restrict__ Ag0,
          const float* __restrict__ Bg0, const float* __restrict__ Cg0,
          float* __restrict__ Yg0) {
  __shared__ unsigned short Bs[2][64 * ST];  // iel[l]*B[l][n]
  __shared__ unsigned short Cs[2][64 * ST];  // C[l][n]
  __shared__ unsigned short BT[2][64 * ST];  // iel[l]*B[l][n], transposed -> [n][l]
  __shared__ unsigned short XT[2][32 * ST];  // X^T[p][l]
  __shared__ unsigned short Gs[64 * ST];     // G[l][s]
  __shared__ unsigned short Sb[2][32 * ST];  // state bf16 copy [p][n]
  __shared__ float elt[4][64], ielt[4][64];  // exp(+-cumsum(A)), mod-4 buffered

  const int tid = threadIdx.x;
  const int blk = ((blockIdx.x & 7) << 5) | (blockIdx.x >> 3);  // XCD co-locate pairs
  const int ph = blk & 1, hi = (blk >> 1) & 31, bi = blk >> 6;

  const float* Xg = Xg0 + ((size_t)bi * Ss * Hh + hi) * HP + ph * 32;
  const float* Bg = Bg0 + ((size_t)bi * Ss * Hh + hi) * HN;
  const float* Cg = Cg0 + ((size_t)bi * Ss * Hh + hi) * HN;
  const float* Ag = Ag0 + (size_t)bi * Ss * Hh + hi;
  float*       Yg = Yg0 + ((size_t)bi * Ss * Hh + hi) * HP + ph * 32;

  const int w = tid >> 6, lane = tid & 63;
  const int lr = lane & 15, lk = lane >> 4;

  // phase-A tile assignment: 10 lower-tri tiles over 8 waves (1,1,1,1,1,1,2,2)
  const int tlA[8] = {0, 1, 1, 2, 2, 2, 3, 3};
  const int tsA[8] = {0, 0, 1, 0, 1, 2, 0, 2};
  const int ntA[8] = {1, 1, 1, 1, 1, 1, 2, 2};

  for (int i = tid; i < 64 * ST; i += 1024) Gs[i] = 0;          // upper tiles stay 0
  for (int i = tid; i < 32 * ST; i += 1024) { Sb[0][i] = 0; Sb[1][i] = 0; }

  float4 rA, rB2, rC1, rC2;  // staging registers

  auto a_scan = [&](int ci) {
    if (tid < 64) {
      float a = Ag[(size_t)(ci * 64 + tid) * Hh];
#pragma unroll
      for (int off = 1; off < 64; off <<= 1) {
        float v = __shfl_up(a, off);
        if (tid >= off) a += v;
      }
      elt[ci & 3][tid] = __expf(a);
      ielt[ci & 3][tid] = __expf(-a);
    }
  };

  auto stage_load = [&](int ci) {
    const size_t rowB = (size_t)ci * 64;
    if (w >= 8) {
      const int u = tid - 512;
      const int r = u >> 3, c = (u & 7) * 4;
      const float* bp = Bg + (rowB + r) * (size_t)(Hh * HN);
      const float* cp = Cg + (rowB + r) * (size_t)(Hh * HN);
      rA  = *(const float4*)(bp + c);
      rB2 = *(const float4*)(bp + c + 32);
      rC1 = *(const float4*)(cp + c);
      rC2 = *(const float4*)(cp + c + 32);
    } else {
      const int r = tid >> 3, c = (tid & 7) * 4;
      rA = *(const float4*)(Xg + (rowB + r) * (size_t)(Hh * HP) + c);
    }
  };

  auto stage_write = [&](int ci) {
    const int buf = ci & 1, nb = ci & 3;
    if (w >= 8) {
      const int u = tid - 512;
      const int r = u >> 3, c = (u & 7) * 4;
      // iel-folded B (both layouts) + raw C
      const float sc = ielt[nb][r];
      float4 s1 = rA;  s1.x *= sc; s1.y *= sc; s1.z *= sc; s1.w *= sc;
      float4 s2 = rB2; s2.x *= sc; s2.y *= sc; s2.z *= sc; s2.w *= sc;
      uint2 t1 = cvt4(s1), t2 = cvt4(s2);
      *(uint2*)&Bs[buf][r * ST + c]      = t1;
      *(uint2*)&Bs[buf][r * ST + c + 32] = t2;
      *(uint2*)&Cs[buf][r * ST + c]      = cvt4(rC1);
      *(uint2*)&Cs[buf][r * ST + c + 32] = cvt4(rC2);
      // B^T: shfl-paired b32 writes (rows r, r^1)
      uint2 u1 = sxor8(t1), u2 = sxor8(t2);
      const unsigned short* m1 = (const unsigned short*)&t1;
      const unsigned short* p1 = (const unsigned short*)&u1;
      const unsigned short* m2 = (const unsigned short*)&t2;
      const unsigned short* p2 = (const unsigned short*)&u2;
      const int g = r & 1, re = r & ~1;
#pragma unroll
      for (int jj = 0; jj < 2; ++jj) {
        const int j = g * 2 + jj;
        unsigned lo1 = g ? p1[j] : m1[j], hi1 = g ? m1[j] : p1[j];
        unsigned lo2 = g ? p2[j] : m2[j], hi2 = g ? m2[j] : p2[j];
        *(unsigned*)&BT[buf][(c + j) * ST + re]      = lo1 | (hi1 << 16);
        *(unsigned*)&BT[buf][(c + 32 + j) * ST + re] = lo2 | (hi2 << 16);
      }
    } else {
      const int r = tid >> 3, c = (tid & 7) * 4;
      uint2 t1 = cvt4(rA);
      uint2 u1 = sxor8(t1);
      const unsigned short* m1 = (const unsigned short*)&t1;
      const unsigned short* p1 = (const unsigned short*)&u1;
      const int g = r & 1, re = r & ~1;
#pragma unroll
      for (int jj = 0; jj < 2; ++jj) {
        const int j = g * 2 + jj;
        unsigned lo = g ? p1[j] : m1[j], hi = g ? m1[j] : p1[j];
        *(unsigned*)&XT[buf][(c + j) * ST + re] = lo | (hi << 16);
      }
    }
  };

  // prologue
  a_scan(0);
  a_scan(1);
  __syncthreads();
  stage_load(0);
  stage_write(0);
  f32x4 Sreg = {0.f, 0.f, 0.f, 0.f};

  for (int ci = 0; ci < NCH; ++ci) {
    const int cur = ci & 1;
    __syncthreads();  // B1: staged cur bufs + tables visible
    if (ci + 1 < NCH) stage_load(ci + 1);   // HBM latency hides under phases
    if (ci + 2 < NCH) a_scan(ci + 2);

    if (w < 8) {
      // ---- phase A: G[l][s] = tril(C.B^T)[l][s] * exp(ac[l]-ac[s]) ----
      // Bs rows carry iel[s] already; multiply el[l] here.
      const int tl = tlA[w];
      const float* el = elt[ci & 3];
#pragma unroll
      for (int t = 0; t < 2; ++t) {
        if (t >= ntA[w]) break;
        const int ts = tsA[w] + t;
        f32x4 acc = {0.f, 0.f, 0.f, 0.f};
#pragma unroll
        for (int ks = 0; ks < 2; ++ks) {
          short8 a = frag(&Cs[cur][(tl * 16 + lr) * ST + ks * 32 + lk * 8]);
          short8 b = frag(&Bs[cur][(ts * 16 + lr) * ST + ks * 32 + lk * 8]);
          acc = __builtin_amdgcn_mfma_f32_16x16x32_bf16(a, b, acc, 0, 0, 0);
        }
        const int gcol = ts * 16 + lr;
#pragma unroll
        for (int i = 0; i < 4; ++i) {
          const int grow = tl * 16 + lk * 4 + i;
          float gv = (gcol <= grow) ? acc[i] * el[grow] : 0.f;
          Gs[grow * ST + gcol] = f2bf(gv);
        }
      }
    } else {
      // ---- phase C: S = ea*(S + X^T.(iel*B)) ; fp32 master in regs ----
      const int u = w - 8, tp = u >> 2, tn = u & 3;
      f32x4 acc = Sreg;
#pragma unroll
      for (int ks = 0; ks < 2; ++ks) {
        short8 a = frag(&XT[cur][(tp * 16 + lr) * ST + ks * 32 + lk * 8]);
        short8 b = frag(&BT[cur][(tn * 16 + lr) * ST + ks * 32 + lk * 8]);
        acc = __builtin_amdgcn_mfma_f32_16x16x32_bf16(a, b, acc, 0, 0, 0);
      }
      const float ea = elt[ci & 3][63];
#pragma unroll
      for (int i = 0; i < 4; ++i) acc[i] *= ea;
      Sreg = acc;
#pragma unroll
      for (int i = 0; i < 4; ++i)
        Sb[(ci + 1) & 1][(tp * 16 + lk * 4 + i) * ST + tn * 16 + lr] = f2bf(acc[i]);
    }

    __syncthreads();  // B2: Gs ready (Sb[nxt] not read until next chunk)

    if (w < 8) {
      // ---- phase B: Y[l][p] = G.X + el[l]*(C.Sb^T) ----
      const int tl = w >> 1, tp = w & 1;
      const size_t rB0 = (size_t)ci * 64;
      f32x4 aD = {0.f, 0.f, 0.f, 0.f}, aO = {0.f, 0.f, 0.f, 0.f};
#pragma unroll
      for (int ks = 0; ks < 2; ++ks) {
        const int ko = ks * 32 + lk * 8;
        short8 gf = frag(&Gs[(tl * 16 + lr) * ST + ko]);
        short8 xf = frag(&XT[cur][(tp * 16 + lr) * ST + ko]);
        aD = __builtin_amdgcn_mfma_f32_16x16x32_bf16(gf, xf, aD, 0, 0, 0);
        short8 cf = frag(&Cs[cur][(tl * 16 + lr) * ST + ko]);
        short8 sf = frag(&Sb[cur][(tp * 16 + lr) * ST + ko]);
        aO = __builtin_amdgcn_mfma_f32_16x16x32_bf16(cf, sf, aO, 0, 0, 0);
      }
      const float* el = elt[ci & 3];
#pragma unroll
      for (int i = 0; i < 4; ++i) {
        const int row = tl * 16 + lk * 4 + i;
        Yg[(rB0 + row) * (size_t)(Hh * HP) + tp * 16 + lr] = aD[i] + el[row] * aO[i];
      }
    }

    if (ci + 1 < NCH) stage_write(ci + 1);  // writes nxt bufs only
  }
}

}  // namespace

extern "C" void kernel_launch(void* const* d_in, const int* in_sizes, int n_in,
                              void* d_out, int out_size, void* d_ws, size_t ws_size,
                              hipStream_t stream) {
  const float* X = (const float*)d_in[0];
  const float* A = (const float*)d_in[1];
  const float* B = (const float*)d_in[2];
  const float* C = (const float*)d_in[3];
  float* Y = (float*)d_out;
  (void)d_ws; (void)ws_size; (void)in_sizes; (void)n_in; (void)out_size;
  ssd4<<<dim3(256), dim3(1024), 0, stream>>>(X, A, B, C, Y);
}

// Round 6
// 282.821 us; speedup vs baseline: 1.2268x; 1.2268x over previous
//
#include <hip/hip_runtime.h>

namespace {

typedef __attribute__((ext_vector_type(8))) short short8;
typedef __attribute__((ext_vector_type(4))) float f32x4;

constexpr int Hh = 32, Ssq = 4096, NCH = 64;
constexpr int GR = 2048;   // global row stride (floats) for X/B/C/Y
constexpr int ST = 68;     // LDS bf16 row stride (8B-aligned rows, odd 8B phase)

__device__ inline unsigned short f2bf(float f) {
  unsigned u = __float_as_uint(f);
  u += 0x7FFFu + ((u >> 16) & 1u);  // RNE
  return (unsigned short)(u >> 16);
}

__device__ inline short8 frag(const unsigned short* p) {
  union { short8 s; uint2 u[2]; } r;
  r.u[0] = *(const uint2*)p;   // rows 8B-aligned: two b64 loads
  r.u[1] = *(const uint2*)(p + 4);
  return r.s;
}

// ---------------- K1: inter-chunk state chain (sequential but tiny) --------
// grid 512 = (b,h,p-quarter); 256 threads (4 waves). State S[p=16][n=64] lives
// in registers (1 n-tile per wave). Per chunk: scan A -> stage X^T and
// iel-folded B^T -> store pre-chunk state (bf16) to ws -> 2 MFMAs -> scale.
__global__ __launch_bounds__(256)
void k1_states(const float* __restrict__ X0, const float* __restrict__ A0,
               const float* __restrict__ B0, unsigned short* __restrict__ S16) {
  __shared__ unsigned short BTs[64 * ST];  // (iel[l]*B[l][n])^T -> [n][l]
  __shared__ unsigned short XTs[16 * ST];  // X^T[p][l]
  __shared__ float ielb[64];
  __shared__ float eab;

  const int tid = threadIdx.x;
  const int pq = blockIdx.x & 3, hi = (blockIdx.x >> 2) & 31, bi = blockIdx.x >> 7;

  const float* Xg = X0 + ((size_t)bi * Ssq * Hh + hi) * 64 + pq * 16;
  const float* Bg = B0 + ((size_t)bi * Ssq * Hh + hi) * 64;
  const float* Ag = A0 + (size_t)bi * Ssq * Hh + hi;
  unsigned short* Sg = S16 + (size_t)(bi * Hh + hi) * NCH * 4096 + pq * 16 * 64;

  const int w = tid >> 6, lane = tid & 63, lr = lane & 15, lk = lane >> 4;
  f32x4 S = {0.f, 0.f, 0.f, 0.f};

  for (int ci = 0; ci < NCH; ++ci) {
    if (tid < 64) {  // A cumsum scan (wave 0)
      float a = Ag[(size_t)(ci * 64 + tid) * Hh];
#pragma unroll
      for (int off = 1; off < 64; off <<= 1) {
        float v = __shfl_up(a, off);
        if (tid >= off) a += v;
      }
      ielb[tid] = __expf(-a);
      if (tid == 63) eab = __expf(a);
    }
    __syncthreads();
    {  // stage
      const int r = tid >> 2, cb = (tid & 3) * 4;
      const float iel = ielb[r];
      const float* bp = Bg + (size_t)(ci * 64 + r) * GR;
#pragma unroll
      for (int j = 0; j < 4; ++j) {
        const int c = cb + 16 * j;
        float4 v = *(const float4*)(bp + c);
        BTs[(c + 0) * ST + r] = f2bf(v.x * iel);
        BTs[(c + 1) * ST + r] = f2bf(v.y * iel);
        BTs[(c + 2) * ST + r] = f2bf(v.z * iel);
        BTs[(c + 3) * ST + r] = f2bf(v.w * iel);
      }
      float4 xv = *(const float4*)(Xg + (size_t)(ci * 64 + r) * GR + cb);
      XTs[(cb + 0) * ST + r] = f2bf(xv.x);
      XTs[(cb + 1) * ST + r] = f2bf(xv.y);
      XTs[(cb + 2) * ST + r] = f2bf(xv.z);
      XTs[(cb + 3) * ST + r] = f2bf(xv.w);
    }
    __syncthreads();
    if (ci) {  // store PRE-chunk state (chunk 0 state is zero -> skipped)
      unsigned short* sp = Sg + (size_t)ci * 4096;
#pragma unroll
      for (int i = 0; i < 4; ++i)
        sp[(lk * 4 + i) * 64 + w * 16 + lr] = f2bf(S[i]);
    }
    f32x4 acc = S;  // S' = ea*(S + X^T.(iel*B))
#pragma unroll
    for (int ks = 0; ks < 2; ++ks)
      acc = __builtin_amdgcn_mfma_f32_16x16x32_bf16(
          frag(&XTs[lr * ST + ks * 32 + lk * 8]),
          frag(&BTs[(w * 16 + lr) * ST + ks * 32 + lk * 8]), acc, 0, 0, 0);
    const float ea = eab;
#pragma unroll
    for (int i = 0; i < 4; ++i) S[i] = acc[i] * ea;
    __syncthreads();  // protect tables/buffers before next chunk overwrites
  }
}

// ---------------- K2: per-chunk Y (fully parallel) --------------------------
// grid 8192 = (b,chunk,h); 256 threads (4 waves); ~35 KB LDS -> 4 blocks/CU.
// Y[l][p] = tril(C.B^T * exp(ac_l - ac_s)).X  +  exp(ac_l) * C.S_in^T
__global__ __launch_bounds__(256, 4)
void k2_y(const float* __restrict__ X0, const float* __restrict__ A0,
          const float* __restrict__ B0, const float* __restrict__ C0,
          const unsigned short* __restrict__ S16, float* __restrict__ Y0) {
  __shared__ unsigned short Cs[64 * ST];   // C[l][n]
  __shared__ unsigned short Bsh[64 * ST];  // iel[s]*B[s][n]
  __shared__ unsigned short XT[64 * ST];   // X^T[p][l]
  __shared__ unsigned short Sb[64 * ST];   // states_in [p][n] (bf16)
  __shared__ unsigned short Gs[64 * ST];   // G[l][s]
  __shared__ float elb[64], ielb2[64];

  const int tid = threadIdx.x;
  const int hi = blockIdx.x & 31, ci = (blockIdx.x >> 5) & 63, bi = blockIdx.x >> 11;

  const float* Xg = X0 + (((size_t)bi * Ssq + ci * 64) * Hh + hi) * 64;
  const float* Bg = B0 + (((size_t)bi * Ssq + ci * 64) * Hh + hi) * 64;
  const float* Cg = C0 + (((size_t)bi * Ssq + ci * 64) * Hh + hi) * 64;
  const float* Ag = A0 + ((size_t)bi * Ssq + ci * 64) * Hh + hi;
  const unsigned short* Sg = S16 + ((size_t)(bi * Hh + hi) * NCH + ci) * 4096;
  float* Yg = Y0 + (((size_t)bi * Ssq + ci * 64) * Hh + hi) * 64;

  const int w = tid >> 6, lane = tid & 63, lr = lane & 15, lk = lane >> 4;

  for (int i = tid; i < 64 * ST; i += 256) Gs[i] = 0;  // upper-tri tiles stay 0

  if (tid < 64) {
    float a = Ag[(size_t)tid * Hh];
#pragma unroll
    for (int off = 1; off < 64; off <<= 1) {
      float v = __shfl_up(a, off);
      if (tid >= off) a += v;
    }
    elb[tid] = __expf(a);
    ielb2[tid] = __expf(-a);
  }
  __syncthreads();

  {  // stage C, iel-folded B (row-major), X^T, Sb
    const int r = tid >> 2, cb = (tid & 3) * 4;
    const float iel = ielb2[r];
    const float* bp = Bg + (size_t)r * GR;
    const float* cp = Cg + (size_t)r * GR;
    const float* xp = Xg + (size_t)r * GR;
#pragma unroll
    for (int j = 0; j < 4; ++j) {
      const int c = cb + 16 * j;
      float4 bv = *(const float4*)(bp + c);
      float4 cv = *(const float4*)(cp + c);
      unsigned short bb[4] = {f2bf(bv.x * iel), f2bf(bv.y * iel),
                              f2bf(bv.z * iel), f2bf(bv.w * iel)};
      unsigned short cc[4] = {f2bf(cv.x), f2bf(cv.y), f2bf(cv.z), f2bf(cv.w)};
      *(uint2*)&Bsh[r * ST + c] = *(const uint2*)bb;
      *(uint2*)&Cs[r * ST + c] = *(const uint2*)cc;
      float4 xv = *(const float4*)(xp + c);
      XT[(c + 0) * ST + r] = f2bf(xv.x);
      XT[(c + 1) * ST + r] = f2bf(xv.y);
      XT[(c + 2) * ST + r] = f2bf(xv.z);
      XT[(c + 3) * ST + r] = f2bf(xv.w);
    }
    if (ci == 0) {
#pragma unroll
      for (int j = 0; j < 4; ++j) {
        const int q = tid + j * 256;  // 1024 x 8B covers 64x64 bf16
        uint2 z = {0u, 0u};
        *(uint2*)&Sb[(q >> 4) * ST + (q & 15) * 4] = z;
      }
    } else {
#pragma unroll
      for (int j = 0; j < 4; ++j) {
        const int q = tid + j * 256;
        *(uint2*)&Sb[(q >> 4) * ST + (q & 15) * 4] = *(const uint2*)(Sg + q * 4);
      }
    }
  }
  __syncthreads();

  {  // phase A: 10 lower-tri G tiles over 4 waves (3,3,2,2)
    int tl[3] = {-1, -1, -1}, ts[3] = {0, 0, 0};
    switch (w) {
      case 0: tl[0] = 0; ts[0] = 0; tl[1] = 1; ts[1] = 0; tl[2] = 1; ts[2] = 1; break;
      case 1: tl[0] = 2; ts[0] = 0; tl[1] = 2; ts[1] = 1; tl[2] = 2; ts[2] = 2; break;
      case 2: tl[0] = 3; ts[0] = 0; tl[1] = 3; ts[1] = 1; break;
      case 3: tl[0] = 3; ts[0] = 2; tl[1] = 3; ts[1] = 3; break;
    }
#pragma unroll
    for (int t = 0; t < 3; ++t) {
      if (tl[t] >= 0) {
        f32x4 acc = {0.f, 0.f, 0.f, 0.f};
#pragma unroll
        for (int ks = 0; ks < 2; ++ks)
          acc = __builtin_amdgcn_mfma_f32_16x16x32_bf16(
              frag(&Cs[(tl[t] * 16 + lr) * ST + ks * 32 + lk * 8]),
              frag(&Bsh[(ts[t] * 16 + lr) * ST + ks * 32 + lk * 8]), acc, 0, 0, 0);
        const int gcol = ts[t] * 16 + lr;
#pragma unroll
        for (int i = 0; i < 4; ++i) {
          const int grow = tl[t] * 16 + lk * 4 + i;
          float gv = (gcol <= grow) ? acc[i] * elb[grow] : 0.f;
          Gs[grow * ST + gcol] = f2bf(gv);
        }
      }
    }
  }
  __syncthreads();

  {  // phase B: wave w owns l-tile w; 4 p-tiles each
#pragma unroll
    for (int tp = 0; tp < 4; ++tp) {
      f32x4 aD = {0.f, 0.f, 0.f, 0.f}, aO = {0.f, 0.f, 0.f, 0.f};
#pragma unroll
      for (int ks = 0; ks < 2; ++ks) {
        const int ko = ks * 32 + lk * 8;
        aD = __builtin_amdgcn_mfma_f32_16x16x32_bf16(
            frag(&Gs[(w * 16 + lr) * ST + ko]), frag(&XT[(tp * 16 + lr) * ST + ko]), aD, 0, 0, 0);
        aO = __builtin_amdgcn_mfma_f32_16x16x32_bf16(
            frag(&Cs[(w * 16 + lr) * ST + ko]), frag(&Sb[(tp * 16 + lr) * ST + ko]), aO, 0, 0, 0);
      }
#pragma unroll
      for (int i = 0; i < 4; ++i) {
        const int row = w * 16 + lk * 4 + i;
        Yg[(size_t)row * GR + tp * 16 + lr] = aD[i] + elb[row] * aO[i];
      }
    }
  }
}

}  // namespace

extern "C" void kernel_launch(void* const* d_in, const int* in_sizes, int n_in,
                              void* d_out, int out_size, void* d_ws, size_t ws_size,
                              hipStream_t stream) {
  const float* X = (const float*)d_in[0];
  const float* A = (const float*)d_in[1];
  const float* B = (const float*)d_in[2];
  const float* C = (const float*)d_in[3];
  float* Y = (float*)d_out;
  unsigned short* S16 = (unsigned short*)d_ws;  // needs 4*32*64*4096*2 = 67 MB
  (void)in_sizes; (void)n_in; (void)out_size; (void)ws_size;
  k1_states<<<dim3(512), dim3(256), 0, stream>>>(X, A, B, S16);
  k2_y<<<dim3(8192), dim3(256), 0, stream>>>(X, A, B, C, S16, Y);
}

// Round 7
// 244.478 us; speedup vs baseline: 1.4192x; 1.1568x over previous
//
#include <hip/hip_runtime.h>

namespace {

typedef __attribute__((ext_vector_type(8))) short short8;
typedef __attribute__((ext_vector_type(4))) float f32x4;

constexpr int Hh = 32, Ssq = 4096, NCH = 64;
constexpr int GR = 2048;   // global row stride (floats) for X/B/C/Y
constexpr int ST = 68;     // LDS bf16 row stride (8B-aligned rows, odd 8B phase)

__device__ inline unsigned short f2bf(float f) {
  unsigned u = __float_as_uint(f);
  u += 0x7FFFu + ((u >> 16) & 1u);  // RNE
  return (unsigned short)(u >> 16);
}
__device__ inline float bf2f(unsigned short s) {
  return __uint_as_float(((unsigned)s) << 16);
}

__device__ inline short8 frag(const unsigned short* p) {
  union { short8 s; uint2 u[2]; } r;
  r.u[0] = *(const uint2*)p;   // rows 8B-aligned: two b64 loads
  r.u[1] = *(const uint2*)(p + 4);
  return r.s;
}

// ---------------- K1a: per-chunk LOCAL state (fully parallel) ---------------
// grid 8192 = (b,chunk,h); 256 threads (4 waves). Writes sl_c = ea*(X^T.(iel*B))
// as bf16 [p][n] to ws slot c. Chunk 63's local state is never consumed -> skip.
__global__ __launch_bounds__(256, 4)
void k1a_chunkstate(const float* __restrict__ X0, const float* __restrict__ A0,
                    const float* __restrict__ B0, unsigned short* __restrict__ S16) {
  __shared__ unsigned short BTs[64 * ST];  // (iel[l]*B[l][n])^T -> [n][l]
  __shared__ unsigned short XTs[64 * ST];  // X^T[p][l]
  __shared__ float ielb[64];
  __shared__ float eab;

  const int tid = threadIdx.x;
  const int hi = blockIdx.x & 31, ci = (blockIdx.x >> 5) & 63, bi = blockIdx.x >> 11;
  if (ci == 63) return;

  const float* Xg = X0 + (((size_t)bi * Ssq + ci * 64) * Hh + hi) * 64;
  const float* Bg = B0 + (((size_t)bi * Ssq + ci * 64) * Hh + hi) * 64;
  const float* Ag = A0 + ((size_t)bi * Ssq + ci * 64) * Hh + hi;
  unsigned short* sp = S16 + ((size_t)(bi * Hh + hi) * NCH + ci) * 4096;

  const int w = tid >> 6, lane = tid & 63, lr = lane & 15, lk = lane >> 4;

  if (tid < 64) {  // A cumsum scan
    float a = Ag[(size_t)tid * Hh];
#pragma unroll
    for (int off = 1; off < 64; off <<= 1) {
      float v = __shfl_up(a, off);
      if (tid >= off) a += v;
    }
    ielb[tid] = __expf(-a);
    if (tid == 63) eab = __expf(a);
  }
  __syncthreads();

  {  // stage X^T and iel-folded B^T (transposed scatter, conflict-free per R6)
    const int r = tid >> 2, cb = (tid & 3) * 4;
    const float iel = ielb[r];
    const float* bp = Bg + (size_t)r * GR;
    const float* xp = Xg + (size_t)r * GR;
#pragma unroll
    for (int j = 0; j < 4; ++j) {
      const int c = cb + 16 * j;
      float4 bv = *(const float4*)(bp + c);
      BTs[(c + 0) * ST + r] = f2bf(bv.x * iel);
      BTs[(c + 1) * ST + r] = f2bf(bv.y * iel);
      BTs[(c + 2) * ST + r] = f2bf(bv.z * iel);
      BTs[(c + 3) * ST + r] = f2bf(bv.w * iel);
      float4 xv = *(const float4*)(xp + c);
      XTs[(c + 0) * ST + r] = f2bf(xv.x);
      XTs[(c + 1) * ST + r] = f2bf(xv.y);
      XTs[(c + 2) * ST + r] = f2bf(xv.z);
      XTs[(c + 3) * ST + r] = f2bf(xv.w);
    }
  }
  __syncthreads();

  const float ea = eab;
#pragma unroll
  for (int tp = 0; tp < 4; ++tp) {  // wave w owns n-tile w; 4 p-tiles each
    f32x4 acc = {0.f, 0.f, 0.f, 0.f};
#pragma unroll
    for (int ks = 0; ks < 2; ++ks)
      acc = __builtin_amdgcn_mfma_f32_16x16x32_bf16(
          frag(&XTs[(tp * 16 + lr) * ST + ks * 32 + lk * 8]),
          frag(&BTs[(w * 16 + lr) * ST + ks * 32 + lk * 8]), acc, 0, 0, 0);
#pragma unroll
    for (int i = 0; i < 4; ++i)
      sp[(tp * 16 + lk * 4 + i) * 64 + w * 16 + lr] = f2bf(acc[i] * ea);
  }
}

// ---------------- K1b: inter-chunk scan (in-place over ws) ------------------
// grid 1024 = (b,h,p-eighth); 256 threads, 2 elems each. S_in[c+1] =
// exp(Atot_c)*S_in[c] + sl_c. Slot c+1 is prefetched (sl_{c+1}) before being
// overwritten with S_in[c+1], so the scan runs in place (ws stays 67 MB).
__global__ __launch_bounds__(256)
void k1b_scan(const float* __restrict__ A0, unsigned short* __restrict__ S16) {
  __shared__ float part[256];
  __shared__ float eat[64];

  const int tid = threadIdx.x;
  const int sl8 = blockIdx.x & 7, hi = (blockIdx.x >> 3) & 31, bi = blockIdx.x >> 8;
  const float* Ag = A0 + (size_t)bi * Ssq * Hh + hi;

  {  // per-chunk A totals: thread (c=tid>>2, q=tid&3) sums 16 values
    const int c = tid >> 2, q = tid & 3;
    float s = 0.f;
#pragma unroll
    for (int k = 0; k < 16; ++k) s += Ag[(size_t)(c * 64 + q * 16 + k) * Hh];
    part[tid] = s;
  }
  __syncthreads();
  if (tid < 64)
    eat[tid] = __expf(part[tid * 4] + part[tid * 4 + 1] + part[tid * 4 + 2] + part[tid * 4 + 3]);
  __syncthreads();

  unsigned short* base =
      S16 + (size_t)(bi * Hh + hi) * NCH * 4096 + sl8 * 512 + tid * 2;
  float s0 = 0.f, s1 = 0.f;
  unsigned cur = *(const unsigned*)base;  // sl_0
  for (int c = 0; c < 63; ++c) {
    unsigned nxt = 0u;
    if (c + 1 < 63) nxt = *(const unsigned*)(base + (size_t)(c + 1) * 4096);  // sl_{c+1}
    const float ea = eat[c];
    s0 = s0 * ea + bf2f((unsigned short)(cur & 0xffffu));
    s1 = s1 * ea + bf2f((unsigned short)(cur >> 16));
    *(unsigned*)(base + (size_t)(c + 1) * 4096) =
        (unsigned)f2bf(s0) | ((unsigned)f2bf(s1) << 16);  // S_in[c+1]
    cur = nxt;
  }
}

// ---------------- K2: per-chunk Y (fully parallel; unchanged from R6) -------
__global__ __launch_bounds__(256, 4)
void k2_y(const float* __restrict__ X0, const float* __restrict__ A0,
          const float* __restrict__ B0, const float* __restrict__ C0,
          const unsigned short* __restrict__ S16, float* __restrict__ Y0) {
  __shared__ unsigned short Cs[64 * ST];   // C[l][n]
  __shared__ unsigned short Bsh[64 * ST];  // iel[s]*B[s][n]
  __shared__ unsigned short XT[64 * ST];   // X^T[p][l]
  __shared__ unsigned short Sb[64 * ST];   // states_in [p][n] (bf16)
  __shared__ unsigned short Gs[64 * ST];   // G[l][s]
  __shared__ float elb[64], ielb2[64];

  const int tid = threadIdx.x;
  const int hi = blockIdx.x & 31, ci = (blockIdx.x >> 5) & 63, bi = blockIdx.x >> 11;

  const float* Xg = X0 + (((size_t)bi * Ssq + ci * 64) * Hh + hi) * 64;
  const float* Bg = B0 + (((size_t)bi * Ssq + ci * 64) * Hh + hi) * 64;
  const float* Cg = C0 + (((size_t)bi * Ssq + ci * 64) * Hh + hi) * 64;
  const float* Ag = A0 + ((size_t)bi * Ssq + ci * 64) * Hh + hi;
  const unsigned short* Sg = S16 + ((size_t)(bi * Hh + hi) * NCH + ci) * 4096;
  float* Yg = Y0 + (((size_t)bi * Ssq + ci * 64) * Hh + hi) * 64;

  const int w = tid >> 6, lane = tid & 63, lr = lane & 15, lk = lane >> 4;

  for (int i = tid; i < 64 * ST; i += 256) Gs[i] = 0;  // upper-tri tiles stay 0

  if (tid < 64) {
    float a = Ag[(size_t)tid * Hh];
#pragma unroll
    for (int off = 1; off < 64; off <<= 1) {
      float v = __shfl_up(a, off);
      if (tid >= off) a += v;
    }
    elb[tid] = __expf(a);
    ielb2[tid] = __expf(-a);
  }
  __syncthreads();

  {  // stage C, iel-folded B (row-major), X^T, Sb
    const int r = tid >> 2, cb = (tid & 3) * 4;
    const float iel = ielb2[r];
    const float* bp = Bg + (size_t)r * GR;
    const float* cp = Cg + (size_t)r * GR;
    const float* xp = Xg + (size_t)r * GR;
#pragma unroll
    for (int j = 0; j < 4; ++j) {
      const int c = cb + 16 * j;
      float4 bv = *(const float4*)(bp + c);
      float4 cv = *(const float4*)(cp + c);
      unsigned short bb[4] = {f2bf(bv.x * iel), f2bf(bv.y * iel),
                              f2bf(bv.z * iel), f2bf(bv.w * iel)};
      unsigned short cc[4] = {f2bf(cv.x), f2bf(cv.y), f2bf(cv.z), f2bf(cv.w)};
      *(uint2*)&Bsh[r * ST + c] = *(const uint2*)bb;
      *(uint2*)&Cs[r * ST + c] = *(const uint2*)cc;
      float4 xv = *(const float4*)(xp + c);
      XT[(c + 0) * ST + r] = f2bf(xv.x);
      XT[(c + 1) * ST + r] = f2bf(xv.y);
      XT[(c + 2) * ST + r] = f2bf(xv.z);
      XT[(c + 3) * ST + r] = f2bf(xv.w);
    }
    if (ci == 0) {
#pragma unroll
      for (int j = 0; j < 4; ++j) {
        const int q = tid + j * 256;  // 1024 x 8B covers 64x64 bf16
        uint2 z = {0u, 0u};
        *(uint2*)&Sb[(q >> 4) * ST + (q & 15) * 4] = z;
      }
    } else {
#pragma unroll
      for (int j = 0; j < 4; ++j) {
        const int q = tid + j * 256;
        *(uint2*)&Sb[(q >> 4) * ST + (q & 15) * 4] = *(const uint2*)(Sg + q * 4);
      }
    }
  }
  __syncthreads();

  {  // phase A: 10 lower-tri G tiles over 4 waves (3,3,2,2)
    int tl[3] = {-1, -1, -1}, ts[3] = {0, 0, 0};
    switch (w) {
      case 0: tl[0] = 0; ts[0] = 0; tl[1] = 1; ts[1] = 0; tl[2] = 1; ts[2] = 1; break;
      case 1: tl[0] = 2; ts[0] = 0; tl[1] = 2; ts[1] = 1; tl[2] = 2; ts[2] = 2; break;
      case 2: tl[0] = 3; ts[0] = 0; tl[1] = 3; ts[1] = 1; break;
      case 3: tl[0] = 3; ts[0] = 2; tl[1] = 3; ts[1] = 3; break;
    }
#pragma unroll
    for (int t = 0; t < 3; ++t) {
      if (tl[t] >= 0) {
        f32x4 acc = {0.f, 0.f, 0.f, 0.f};
#pragma unroll
        for (int ks = 0; ks < 2; ++ks)
          acc = __builtin_amdgcn_mfma_f32_16x16x32_bf16(
              frag(&Cs[(tl[t] * 16 + lr) * ST + ks * 32 + lk * 8]),
              frag(&Bsh[(ts[t] * 16 + lr) * ST + ks * 32 + lk * 8]), acc, 0, 0, 0);
        const int gcol = ts[t] * 16 + lr;
#pragma unroll
        for (int i = 0; i < 4; ++i) {
          const int grow = tl[t] * 16 + lk * 4 + i;
          float gv = (gcol <= grow) ? acc[i] * elb[grow] : 0.f;
          Gs[grow * ST + gcol] = f2bf(gv);
        }
      }
    }
  }
  __syncthreads();

  {  // phase B: wave w owns l-tile w; 4 p-tiles each
#pragma unroll
    for (int tp = 0; tp < 4; ++tp) {
      f32x4 aD = {0.f, 0.f, 0.f, 0.f}, aO = {0.f, 0.f, 0.f, 0.f};
#pragma unroll
      for (int ks = 0; ks < 2; ++ks) {
        const int ko = ks * 32 + lk * 8;
        aD = __builtin_amdgcn_mfma_f32_16x16x32_bf16(
            frag(&Gs[(w * 16 + lr) * ST + ko]), frag(&XT[(tp * 16 + lr) * ST + ko]), aD, 0, 0, 0);
        aO = __builtin_amdgcn_mfma_f32_16x16x32_bf16(
            frag(&Cs[(w * 16 + lr) * ST + ko]), frag(&Sb[(tp * 16 + lr) * ST + ko]), aO, 0, 0, 0);
      }
#pragma unroll
      for (int i = 0; i < 4; ++i) {
        const int row = w * 16 + lk * 4 + i;
        Yg[(size_t)row * GR + tp * 16 + lr] = aD[i] + elb[row] * aO[i];
      }
    }
  }
}

}  // namespace

extern "C" void kernel_launch(void* const* d_in, const int* in_sizes, int n_in,
                              void* d_out, int out_size, void* d_ws, size_t ws_size,
                              hipStream_t stream) {
  const float* X = (const float*)d_in[0];
  const float* A = (const float*)d_in[1];
  const float* B = (const float*)d_in[2];
  const float* C = (const float*)d_in[3];
  float* Y = (float*)d_out;
  unsigned short* S16 = (unsigned short*)d_ws;  // 4*32*64*4096*2 = 67 MB (as R6)
  (void)in_sizes; (void)n_in; (void)out_size; (void)ws_size;
  k1a_chunkstate<<<dim3(8192), dim3(256), 0, stream>>>(X, A, B, S16);
  k1b_scan<<<dim3(1024), dim3(256), 0, stream>>>(A, S16);
  k2_y<<<dim3(8192), dim3(256), 0, stream>>>(X, A, B, C, S16, Y);
}

// Round 8
// 241.442 us; speedup vs baseline: 1.4371x; 1.0126x over previous
//
#include <hip/hip_runtime.h>

namespace {

typedef __attribute__((ext_vector_type(8))) short short8;
typedef __attribute__((ext_vector_type(4))) float f32x4;

constexpr int Hh = 32, Ssq = 4096, NCH = 64;
constexpr int GR = 2048;   // global row stride (floats) for X/B/C/Y
constexpr int ST = 68;     // LDS bf16 row stride (8B-aligned rows, odd 8B phase)

__device__ inline unsigned short f2bf(float f) {
  unsigned u = __float_as_uint(f);
  u += 0x7FFFu + ((u >> 16) & 1u);  // RNE
  return (unsigned short)(u >> 16);
}
__device__ inline float bf2f(unsigned short s) {
  return __uint_as_float(((unsigned)s) << 16);
}

__device__ inline short8 frag(const unsigned short* p) {
  union { short8 s; uint2 u[2]; } r;
  r.u[0] = *(const uint2*)p;   // rows 8B-aligned: two b64 loads
  r.u[1] = *(const uint2*)(p + 4);
  return r.s;
}

// ---------------- K1a: per-chunk LOCAL state (fully parallel) ---------------
// grid 8192 = (b,chunk,h); 256 threads (4 waves). Writes sl_c = ea*(X^T.(iel*B))
// as bf16 [p][n] to ws slot c. LDS ~18 KB, VGPR 40 -> 8 blocks/CU allowed.
__global__ __launch_bounds__(256, 8)
void k1a_chunkstate(const float* __restrict__ X0, const float* __restrict__ A0,
                    const float* __restrict__ B0, unsigned short* __restrict__ S16) {
  __shared__ unsigned short BTs[64 * ST];  // (iel[l]*B[l][n])^T -> [n][l]
  __shared__ unsigned short XTs[64 * ST];  // X^T[p][l]
  __shared__ float ielb[64];
  __shared__ float eab;

  const int tid = threadIdx.x;
  const int hi = blockIdx.x & 31, ci = (blockIdx.x >> 5) & 63, bi = blockIdx.x >> 11;
  if (ci == 63) return;  // chunk 63's local state is never consumed

  const float* Xg = X0 + (((size_t)bi * Ssq + ci * 64) * Hh + hi) * 64;
  const float* Bg = B0 + (((size_t)bi * Ssq + ci * 64) * Hh + hi) * 64;
  const float* Ag = A0 + ((size_t)bi * Ssq + ci * 64) * Hh + hi;
  unsigned short* sp = S16 + ((size_t)(bi * Hh + hi) * NCH + ci) * 4096;

  const int w = tid >> 6, lane = tid & 63, lr = lane & 15, lk = lane >> 4;

  if (tid < 64) {  // A cumsum scan
    float a = Ag[(size_t)tid * Hh];
#pragma unroll
    for (int off = 1; off < 64; off <<= 1) {
      float v = __shfl_up(a, off);
      if (tid >= off) a += v;
    }
    ielb[tid] = __expf(-a);
    if (tid == 63) eab = __expf(a);
  }
  __syncthreads();

  {  // stage X^T and iel-folded B^T
    const int r = tid >> 2, cb = (tid & 3) * 4;
    const float iel = ielb[r];
    const float* bp = Bg + (size_t)r * GR;
    const float* xp = Xg + (size_t)r * GR;
#pragma unroll
    for (int j = 0; j < 4; ++j) {
      const int c = cb + 16 * j;
      float4 bv = *(const float4*)(bp + c);
      BTs[(c + 0) * ST + r] = f2bf(bv.x * iel);
      BTs[(c + 1) * ST + r] = f2bf(bv.y * iel);
      BTs[(c + 2) * ST + r] = f2bf(bv.z * iel);
      BTs[(c + 3) * ST + r] = f2bf(bv.w * iel);
      float4 xv = *(const float4*)(xp + c);
      XTs[(c + 0) * ST + r] = f2bf(xv.x);
      XTs[(c + 1) * ST + r] = f2bf(xv.y);
      XTs[(c + 2) * ST + r] = f2bf(xv.z);
      XTs[(c + 3) * ST + r] = f2bf(xv.w);
    }
  }
  __syncthreads();

  const float ea = eab;
#pragma unroll
  for (int tp = 0; tp < 4; ++tp) {  // wave w owns n-tile w; 4 p-tiles each
    f32x4 acc = {0.f, 0.f, 0.f, 0.f};
#pragma unroll
    for (int ks = 0; ks < 2; ++ks)
      acc = __builtin_amdgcn_mfma_f32_16x16x32_bf16(
          frag(&XTs[(tp * 16 + lr) * ST + ks * 32 + lk * 8]),
          frag(&BTs[(w * 16 + lr) * ST + ks * 32 + lk * 8]), acc, 0, 0, 0);
#pragma unroll
    for (int i = 0; i < 4; ++i)
      sp[(tp * 16 + lk * 4 + i) * 64 + w * 16 + lr] = f2bf(acc[i] * ea);
  }
}

// ---------------- K1b: inter-chunk scan (in-place, 4-deep prefetch) ---------
// grid 1024 = (b,h,p-eighth); 256 threads, 1 dword (2 elems) each.
// S_in[c+1] = exp(Atot_c)*S_in[c] + sl_c, run in place over ws. sl loads are
// independent of the FMA chain: keep 4 in flight (named regs, static unroll).
__global__ __launch_bounds__(256)
void k1b_scan(const float* __restrict__ A0, unsigned short* __restrict__ S16) {
  __shared__ float part[256];
  __shared__ float eat[64];

  const int tid = threadIdx.x;
  const int sl8 = blockIdx.x & 7, hi = (blockIdx.x >> 3) & 31, bi = blockIdx.x >> 8;
  const float* Ag = A0 + (size_t)bi * Ssq * Hh + hi;

  {  // per-chunk A totals
    const int c = tid >> 2, q = tid & 3;
    float s = 0.f;
#pragma unroll
    for (int k = 0; k < 16; ++k) s += Ag[(size_t)(c * 64 + q * 16 + k) * Hh];
    part[tid] = s;
  }
  __syncthreads();
  if (tid < 64)
    eat[tid] = __expf(part[tid * 4] + part[tid * 4 + 1] + part[tid * 4 + 2] + part[tid * 4 + 3]);
  __syncthreads();

  unsigned short* base =
      S16 + (size_t)(bi * Hh + hi) * NCH * 4096 + sl8 * 512 + tid * 2;
  float s0 = 0.f, s1 = 0.f;

  auto L = [&](int c) -> unsigned {
    return (c < 63) ? *(const unsigned*)(base + (size_t)c * 4096) : 0u;
  };
  auto step = [&](int c, unsigned v) {
    const float ea = eat[c];
    s0 = s0 * ea + bf2f((unsigned short)(v & 0xffffu));
    s1 = s1 * ea + bf2f((unsigned short)(v >> 16));
    *(unsigned*)(base + (size_t)(c + 1) * 4096) =
        (unsigned)f2bf(s0) | ((unsigned)f2bf(s1) << 16);
  };

  unsigned q0 = L(0), q1 = L(1), q2 = L(2), q3 = L(3);
  for (int c = 0; c < 60; c += 4) {  // steps 0..59
    step(c + 0, q0); q0 = L(c + 4);
    step(c + 1, q1); q1 = L(c + 5);
    step(c + 2, q2); q2 = L(c + 6);
    step(c + 3, q3); q3 = L(c + 7);
  }
  step(60, q0); step(61, q1); step(62, q2);  // 63 steps total, stores slots 1..63
}

// ---------------- K2: per-chunk Y (fully parallel) --------------------------
// grid 8192 = (b,chunk,h); 256 threads (4 waves). Gs array eliminated: phase-A
// accs stay in registers; after a barrier ending all Bsh reads, G (+ zero
// upper tiles) is written INTO Bsh. LDS 35.3 KB -> 4 blocks/CU.
__global__ __launch_bounds__(256, 4)
void k2_y(const float* __restrict__ X0, const float* __restrict__ A0,
          const float* __restrict__ B0, const float* __restrict__ C0,
          const unsigned short* __restrict__ S16, float* __restrict__ Y0) {
  __shared__ unsigned short Cs[64 * ST];   // C[l][n]
  __shared__ unsigned short Bsh[64 * ST];  // iel[s]*B[s][n]; later G[l][s]
  __shared__ unsigned short XT[64 * ST];   // X^T[p][l]
  __shared__ unsigned short Sb[64 * ST];   // states_in [p][n] (bf16)
  __shared__ float elb[64], ielb2[64];

  const int tid = threadIdx.x;
  const int hi = blockIdx.x & 31, ci = (blockIdx.x >> 5) & 63, bi = blockIdx.x >> 11;

  const float* Xg = X0 + (((size_t)bi * Ssq + ci * 64) * Hh + hi) * 64;
  const float* Bg = B0 + (((size_t)bi * Ssq + ci * 64) * Hh + hi) * 64;
  const float* Cg = C0 + (((size_t)bi * Ssq + ci * 64) * Hh + hi) * 64;
  const float* Ag = A0 + ((size_t)bi * Ssq + ci * 64) * Hh + hi;
  const unsigned short* Sg = S16 + ((size_t)(bi * Hh + hi) * NCH + ci) * 4096;
  float* Yg = Y0 + (((size_t)bi * Ssq + ci * 64) * Hh + hi) * 64;

  const int w = tid >> 6, lane = tid & 63, lr = lane & 15, lk = lane >> 4;

  if (tid < 64) {
    float a = Ag[(size_t)tid * Hh];
#pragma unroll
    for (int off = 1; off < 64; off <<= 1) {
      float v = __shfl_up(a, off);
      if (tid >= off) a += v;
    }
    elb[tid] = __expf(a);
    ielb2[tid] = __expf(-a);
  }
  __syncthreads();

  {  // stage C, iel-folded B (row-major), X^T, Sb
    const int r = tid >> 2, cb = (tid & 3) * 4;
    const float iel = ielb2[r];
    const float* bp = Bg + (size_t)r * GR;
    const float* cp = Cg + (size_t)r * GR;
    const float* xp = Xg + (size_t)r * GR;
#pragma unroll
    for (int j = 0; j < 4; ++j) {
      const int c = cb + 16 * j;
      float4 bv = *(const float4*)(bp + c);
      float4 cv = *(const float4*)(cp + c);
      unsigned short bb[4] = {f2bf(bv.x * iel), f2bf(bv.y * iel),
                              f2bf(bv.z * iel), f2bf(bv.w * iel)};
      unsigned short cc[4] = {f2bf(cv.x), f2bf(cv.y), f2bf(cv.z), f2bf(cv.w)};
      *(uint2*)&Bsh[r * ST + c] = *(const uint2*)bb;
      *(uint2*)&Cs[r * ST + c] = *(const uint2*)cc;
      float4 xv = *(const float4*)(xp + c);
      XT[(c + 0) * ST + r] = f2bf(xv.x);
      XT[(c + 1) * ST + r] = f2bf(xv.y);
      XT[(c + 2) * ST + r] = f2bf(xv.z);
      XT[(c + 3) * ST + r] = f2bf(xv.w);
    }
    if (ci == 0) {
#pragma unroll
      for (int j = 0; j < 4; ++j) {
        const int q = tid + j * 256;  // 1024 x 8B covers 64x64 bf16
        uint2 z = {0u, 0u};
        *(uint2*)&Sb[(q >> 4) * ST + (q & 15) * 4] = z;
      }
    } else {
#pragma unroll
      for (int j = 0; j < 4; ++j) {
        const int q = tid + j * 256;
        *(uint2*)&Sb[(q >> 4) * ST + (q & 15) * 4] = *(const uint2*)(Sg + q * 4);
      }
    }
  }
  __syncthreads();

  // phase A compute: 10 lower-tri G tiles over 4 waves (3,3,2,2), accs in regs
  int tl[3] = {-1, -1, -1}, ts[3] = {0, 0, 0};
  int zr[2] = {-1, -1}, zc[2] = {0, 0};  // strictly-upper zero tiles
  switch (w) {
    case 0: tl[0] = 0; ts[0] = 0; tl[1] = 1; ts[1] = 0; tl[2] = 1; ts[2] = 1;
            zr[0] = 0; zc[0] = 1; zr[1] = 0; zc[1] = 2; break;
    case 1: tl[0] = 2; ts[0] = 0; tl[1] = 2; ts[1] = 1; tl[2] = 2; ts[2] = 2;
            zr[0] = 0; zc[0] = 3; break;
    case 2: tl[0] = 3; ts[0] = 0; tl[1] = 3; ts[1] = 1;
            zr[0] = 1; zc[0] = 2; zr[1] = 1; zc[1] = 3; break;
    case 3: tl[0] = 3; ts[0] = 2; tl[1] = 3; ts[1] = 3;
            zr[0] = 2; zc[0] = 3; break;
  }
  f32x4 ga[3];
#pragma unroll
  for (int t = 0; t < 3; ++t) {
    ga[t] = (f32x4){0.f, 0.f, 0.f, 0.f};
    if (tl[t] >= 0) {
#pragma unroll
      for (int ks = 0; ks < 2; ++ks)
        ga[t] = __builtin_amdgcn_mfma_f32_16x16x32_bf16(
            frag(&Cs[(tl[t] * 16 + lr) * ST + ks * 32 + lk * 8]),
            frag(&Bsh[(ts[t] * 16 + lr) * ST + ks * 32 + lk * 8]), ga[t], 0, 0, 0);
    }
  }
  __syncthreads();  // all reads of Bsh (staged B) done

  {  // write G (masked, el-scaled) + zero upper tiles into Bsh
#pragma unroll
    for (int t = 0; t < 3; ++t) {
      if (tl[t] >= 0) {
        const int gcol = ts[t] * 16 + lr;
#pragma unroll
        for (int i = 0; i < 4; ++i) {
          const int grow = tl[t] * 16 + lk * 4 + i;
          float gv = (gcol <= grow) ? ga[t][i] * elb[grow] : 0.f;
          Bsh[grow * ST + gcol] = f2bf(gv);
        }
      }
    }
    const int zrow = lane >> 2, zq = lane & 3;
    uint2 z = {0u, 0u};
#pragma unroll
    for (int t = 0; t < 2; ++t)
      if (zr[t] >= 0)
        *(uint2*)&Bsh[(zr[t] * 16 + zrow) * ST + zc[t] * 16 + zq * 4] = z;
  }
  __syncthreads();  // G ready

  {  // phase B: wave w owns l-tile w; 4 p-tiles each
#pragma unroll
    for (int tp = 0; tp < 4; ++tp) {
      f32x4 aD = {0.f, 0.f, 0.f, 0.f}, aO = {0.f, 0.f, 0.f, 0.f};
#pragma unroll
      for (int ks = 0; ks < 2; ++ks) {
        const int ko = ks * 32 + lk * 8;
        aD = __builtin_amdgcn_mfma_f32_16x16x32_bf16(
            frag(&Bsh[(w * 16 + lr) * ST + ko]), frag(&XT[(tp * 16 + lr) * ST + ko]), aD, 0, 0, 0);
        aO = __builtin_amdgcn_mfma_f32_16x16x32_bf16(
            frag(&Cs[(w * 16 + lr) * ST + ko]), frag(&Sb[(tp * 16 + lr) * ST + ko]), aO, 0, 0, 0);
      }
#pragma unroll
      for (int i = 0; i < 4; ++i) {
        const int row = w * 16 + lk * 4 + i;
        Yg[(size_t)row * GR + tp * 16 + lr] = aD[i] + elb[row] * aO[i];
      }
    }
  }
}

}  // namespace

extern "C" void kernel_launch(void* const* d_in, const int* in_sizes, int n_in,
                              void* d_out, int out_size, void* d_ws, size_t ws_size,
                              hipStream_t stream) {
  const float* X = (const float*)d_in[0];
  const float* A = (const float*)d_in[1];
  const float* B = (const float*)d_in[2];
  const float* C = (const float*)d_in[3];
  float* Y = (float*)d_out;
  unsigned short* S16 = (unsigned short*)d_ws;  // 4*32*64*4096*2 = 67 MB
  (void)in_sizes; (void)n_in; (void)out_size; (void)ws_size;
  k1a_chunkstate<<<dim3(8192), dim3(256), 0, stream>>>(X, A, B, S16);
  k1b_scan<<<dim3(1024), dim3(256), 0, stream>>>(A, S16);
  k2_y<<<dim3(8192), dim3(256), 0, stream>>>(X, A, B, C, S16, Y);
}

// Round 9
// 240.845 us; speedup vs baseline: 1.4406x; 1.0025x over previous
//
#include <hip/hip_runtime.h>

namespace {

typedef __attribute__((ext_vector_type(8))) short short8;
typedef __attribute__((ext_vector_type(16))) float f32x16;

constexpr int Hh = 32, Ssq = 4096, NCH = 64;
constexpr int GR = 2048;  // global row stride (floats) for X/B/C/Y
constexpr int ST = 72;    // LDS bf16 row stride: 144B, 16B-aligned rows (b128 frags)

__device__ inline unsigned short f2bf(float f) {
  unsigned u = __float_as_uint(f);
  u += 0x7FFFu + ((u >> 16) & 1u);  // RNE
  return (unsigned short)(u >> 16);
}
__device__ inline float bf2f(unsigned short s) {
  return __uint_as_float(((unsigned)s) << 16);
}

// 32x32x16 bf16 MFMA operand helpers: A/B frag = 8 contiguous bf16 (16B) from a
// row-major [row][k] array; lane l -> row (l&31), k-slice ks*16 + (l>>5)*8.
__device__ inline short8 frag128(const unsigned short* base, int row, int ks, int lhi) {
  return *(const short8*)(base + row * ST + ks * 16 + lhi * 8);
}

// ---------------- K1a: per-chunk LOCAL state (fully parallel) ---------------
// grid 8192 = (b,chunk,h); 256 threads (4 waves). sl_c = ea*(X^T.(iel*B)) as
// bf16 [p][n] -> ws slot c. 32x32x16 MFMA: wave w owns tile (p32=w>>1, n32=w&1).
__global__ __launch_bounds__(256, 8)
void k1a_chunkstate(const float* __restrict__ X0, const float* __restrict__ A0,
                    const float* __restrict__ B0, unsigned short* __restrict__ S16) {
  __shared__ __align__(16) unsigned short BTs[64 * ST];  // (iel*B)^T -> [n][l]
  __shared__ __align__(16) unsigned short XTs[64 * ST];  // X^T[p][l]
  __shared__ float ielb[64];
  __shared__ float eab;

  const int tid = threadIdx.x;
  const int hi = blockIdx.x & 31, ci = (blockIdx.x >> 5) & 63, bi = blockIdx.x >> 11;
  if (ci == 63) return;  // chunk 63's local state is never consumed

  const float* Xg = X0 + (((size_t)bi * Ssq + ci * 64) * Hh + hi) * 64;
  const float* Bg = B0 + (((size_t)bi * Ssq + ci * 64) * Hh + hi) * 64;
  const float* Ag = A0 + ((size_t)bi * Ssq + ci * 64) * Hh + hi;
  unsigned short* sp = S16 + ((size_t)(bi * Hh + hi) * NCH + ci) * 4096;

  const int w = tid >> 6, lane = tid & 63;
  const int l31 = lane & 31, lhi = lane >> 5;

  if (tid < 64) {  // A cumsum scan
    float a = Ag[(size_t)tid * Hh];
#pragma unroll
    for (int off = 1; off < 64; off <<= 1) {
      float v = __shfl_up(a, off);
      if (tid >= off) a += v;
    }
    ielb[tid] = __expf(-a);
    if (tid == 63) eab = __expf(a);
  }
  __syncthreads();

  {  // stage X^T and iel-folded B^T (b16 scatter; proven pattern)
    const int r = tid >> 2, cb = (tid & 3) * 4;
    const float iel = ielb[r];
    const float* bp = Bg + (size_t)r * GR;
    const float* xp = Xg + (size_t)r * GR;
#pragma unroll
    for (int j = 0; j < 4; ++j) {
      const int c = cb + 16 * j;
      float4 bv = *(const float4*)(bp + c);
      BTs[(c + 0) * ST + r] = f2bf(bv.x * iel);
      BTs[(c + 1) * ST + r] = f2bf(bv.y * iel);
      BTs[(c + 2) * ST + r] = f2bf(bv.z * iel);
      BTs[(c + 3) * ST + r] = f2bf(bv.w * iel);
      float4 xv = *(const float4*)(xp + c);
      XTs[(c + 0) * ST + r] = f2bf(xv.x);
      XTs[(c + 1) * ST + r] = f2bf(xv.y);
      XTs[(c + 2) * ST + r] = f2bf(xv.z);
      XTs[(c + 3) * ST + r] = f2bf(xv.w);
    }
  }
  __syncthreads();

  const int tp = w >> 1, tn = w & 1;  // 32x32 output tile
  f32x16 acc = {};
#pragma unroll
  for (int ks = 0; ks < 4; ++ks)
    acc = __builtin_amdgcn_mfma_f32_32x32x16_bf16(
        frag128(XTs, 32 * tp + l31, ks, lhi),   // A[i=p][k=l]
        frag128(BTs, 32 * tn + l31, ks, lhi),   // B[k=l][j=n] = BT row n
        acc, 0, 0, 0);
  const float ea = eab;
#pragma unroll
  for (int i = 0; i < 16; ++i) {
    const int p = 32 * tp + (i & 3) + 8 * (i >> 2) + 4 * lhi;
    sp[p * 64 + 32 * tn + l31] = f2bf(acc[i] * ea);
  }
}

// ---------------- K1b: inter-chunk scan (in-place, 4-deep prefetch) ---------
__global__ __launch_bounds__(256)
void k1b_scan(const float* __restrict__ A0, unsigned short* __restrict__ S16) {
  __shared__ float part[256];
  __shared__ float eat[64];

  const int tid = threadIdx.x;
  const int sl8 = blockIdx.x & 7, hi = (blockIdx.x >> 3) & 31, bi = blockIdx.x >> 8;
  const float* Ag = A0 + (size_t)bi * Ssq * Hh + hi;

  {  // per-chunk A totals
    const int c = tid >> 2, q = tid & 3;
    float s = 0.f;
#pragma unroll
    for (int k = 0; k < 16; ++k) s += Ag[(size_t)(c * 64 + q * 16 + k) * Hh];
    part[tid] = s;
  }
  __syncthreads();
  if (tid < 64)
    eat[tid] = __expf(part[tid * 4] + part[tid * 4 + 1] + part[tid * 4 + 2] + part[tid * 4 + 3]);
  __syncthreads();

  unsigned short* base =
      S16 + (size_t)(bi * Hh + hi) * NCH * 4096 + sl8 * 512 + tid * 2;
  float s0 = 0.f, s1 = 0.f;

  auto L = [&](int c) -> unsigned {
    return (c < 63) ? *(const unsigned*)(base + (size_t)c * 4096) : 0u;
  };
  auto step = [&](int c, unsigned v) {
    const float ea = eat[c];
    s0 = s0 * ea + bf2f((unsigned short)(v & 0xffffu));
    s1 = s1 * ea + bf2f((unsigned short)(v >> 16));
    *(unsigned*)(base + (size_t)(c + 1) * 4096) =
        (unsigned)f2bf(s0) | ((unsigned)f2bf(s1) << 16);
  };

  unsigned q0 = L(0), q1 = L(1), q2 = L(2), q3 = L(3);
  for (int c = 0; c < 60; c += 4) {
    step(c + 0, q0); q0 = L(c + 4);
    step(c + 1, q1); q1 = L(c + 5);
    step(c + 2, q2); q2 = L(c + 6);
    step(c + 3, q3); q3 = L(c + 7);
  }
  step(60, q0); step(61, q1); step(62, q2);
}

// ---------------- K2: per-chunk Y (fully parallel, 32x32 MFMA) --------------
// grid 8192 = (b,chunk,h); 256 threads (4 waves). LDS: Cs, Bsh(->G), XT only
// (27.6 KB -> 5 blocks/CU). S_in fragments load straight from global (bf16,
// [p][n] rows are exactly the B-operand layout). Phase A: 3 tril tiles on
// waves 0-2; wave 3 zeroes the upper tile. Phase B: wave w -> Y tile
// (w>>1, w&1), 8 MFMA.
__global__ __launch_bounds__(256, 5)
void k2_y(const float* __restrict__ X0, const float* __restrict__ A0,
          const float* __restrict__ B0, const float* __restrict__ C0,
          const unsigned short* __restrict__ S16, float* __restrict__ Y0) {
  __shared__ __align__(16) unsigned short Cs[64 * ST];   // C[l][n]
  __shared__ __align__(16) unsigned short Bsh[64 * ST];  // iel[s]*B[s][n]; later G[l][s]
  __shared__ __align__(16) unsigned short XT[64 * ST];   // X^T[p][l]
  __shared__ float elb[64], ielb2[64];

  const int tid = threadIdx.x;
  const int hi = blockIdx.x & 31, ci = (blockIdx.x >> 5) & 63, bi = blockIdx.x >> 11;

  const float* Xg = X0 + (((size_t)bi * Ssq + ci * 64) * Hh + hi) * 64;
  const float* Bg = B0 + (((size_t)bi * Ssq + ci * 64) * Hh + hi) * 64;
  const float* Cg = C0 + (((size_t)bi * Ssq + ci * 64) * Hh + hi) * 64;
  const float* Ag = A0 + ((size_t)bi * Ssq + ci * 64) * Hh + hi;
  const unsigned short* Sg = S16 + ((size_t)(bi * Hh + hi) * NCH + ci) * 4096;
  float* Yg = Y0 + (((size_t)bi * Ssq + ci * 64) * Hh + hi) * 64;

  const int w = tid >> 6, lane = tid & 63;
  const int l31 = lane & 31, lhi = lane >> 5;

  if (tid < 64) {
    float a = Ag[(size_t)tid * Hh];
#pragma unroll
    for (int off = 1; off < 64; off <<= 1) {
      float v = __shfl_up(a, off);
      if (tid >= off) a += v;
    }
    elb[tid] = __expf(a);
    ielb2[tid] = __expf(-a);
  }
  __syncthreads();

  {  // stage C, iel-folded B (row-major), X^T
    const int r = tid >> 2, cb = (tid & 3) * 4;
    const float iel = ielb2[r];
    const float* bp = Bg + (size_t)r * GR;
    const float* cp = Cg + (size_t)r * GR;
    const float* xp = Xg + (size_t)r * GR;
#pragma unroll
    for (int j = 0; j < 4; ++j) {
      const int c = cb + 16 * j;
      float4 bv = *(const float4*)(bp + c);
      float4 cv = *(const float4*)(cp + c);
      unsigned short bb[4] = {f2bf(bv.x * iel), f2bf(bv.y * iel),
                              f2bf(bv.z * iel), f2bf(bv.w * iel)};
      unsigned short cc[4] = {f2bf(cv.x), f2bf(cv.y), f2bf(cv.z), f2bf(cv.w)};
      *(uint2*)&Bsh[r * ST + c] = *(const uint2*)bb;
      *(uint2*)&Cs[r * ST + c] = *(const uint2*)cc;
      float4 xv = *(const float4*)(xp + c);
      XT[(c + 0) * ST + r] = f2bf(xv.x);
      XT[(c + 1) * ST + r] = f2bf(xv.y);
      XT[(c + 2) * ST + r] = f2bf(xv.z);
      XT[(c + 3) * ST + r] = f2bf(xv.w);
    }
  }
  __syncthreads();

  // phase A compute: tiles (0,0),(1,0),(1,1) on waves 0-2; wave 3 idle here
  const int ati = (w == 0) ? 0 : 1;          // tile row
  const int atj = (w == 2) ? 1 : 0;          // tile col
  f32x16 ga = {};
  if (w < 3) {
#pragma unroll
    for (int ks = 0; ks < 4; ++ks)
      ga = __builtin_amdgcn_mfma_f32_32x32x16_bf16(
          frag128(Cs, 32 * ati + l31, ks, lhi),    // A[i=l][k=n]
          frag128(Bsh, 32 * atj + l31, ks, lhi),   // B[k=n][j=s] = Bsh row s
          ga, 0, 0, 0);
  }
  __syncthreads();  // all reads of Bsh (staged B) done

  if (w < 3) {  // write G (masked, el-scaled) into Bsh
    const int gcol = 32 * atj + l31;
#pragma unroll
    for (int i = 0; i < 16; ++i) {
      const int grow = 32 * ati + (i & 3) + 8 * (i >> 2) + 4 * lhi;
      float gv = (gcol <= grow) ? ga[i] * elb[grow] : 0.f;
      Bsh[grow * ST + gcol] = f2bf(gv);
    }
  } else {  // zero the strictly-upper tile: rows 0-31, cols 32-63
    const short8 z8 = {};
    *(short8*)&Bsh[l31 * ST + 32 + lhi * 16] = z8;
    *(short8*)&Bsh[l31 * ST + 40 + lhi * 16] = z8;
  }
  __syncthreads();  // G ready

  {  // phase B: wave w -> Y tile (ti=w>>1, tj=w&1)
    const int ti = w >> 1, tj = w & 1;
    short8 sf[4];
    if (ci != 0) {  // S_in fragment: global bf16 [p][n], row = p, 16B contig
      const unsigned short* srow = Sg + (32 * tj + l31) * 64;
#pragma unroll
      for (int ks = 0; ks < 4; ++ks)
        sf[ks] = *(const short8*)(srow + ks * 16 + lhi * 8);
    }
    f32x16 aD = {}, aO = {};
#pragma unroll
    for (int ks = 0; ks < 4; ++ks)
      aD = __builtin_amdgcn_mfma_f32_32x32x16_bf16(
          frag128(Bsh, 32 * ti + l31, ks, lhi),   // A = G rows l
          frag128(XT, 32 * tj + l31, ks, lhi),    // B[k=s][j=p] = XT row p
          aD, 0, 0, 0);
    if (ci != 0) {
#pragma unroll
      for (int ks = 0; ks < 4; ++ks)
        aO = __builtin_amdgcn_mfma_f32_32x32x16_bf16(
            frag128(Cs, 32 * ti + l31, ks, lhi),  // A = C rows l
            sf[ks],                               // B[k=n][j=p] = S row p
            aO, 0, 0, 0);
    }
#pragma unroll
    for (int i = 0; i < 16; ++i) {
      const int row = 32 * ti + (i & 3) + 8 * (i >> 2) + 4 * lhi;
      Yg[(size_t)row * GR + 32 * tj + l31] = aD[i] + elb[row] * aO[i];
    }
  }
}

}  // namespace

extern "C" void kernel_launch(void* const* d_in, const int* in_sizes, int n_in,
                              void* d_out, int out_size, void* d_ws, size_t ws_size,
                              hipStream_t stream) {
  const float* X = (const float*)d_in[0];
  const float* A = (const float*)d_in[1];
  const float* B = (const float*)d_in[2];
  const float* C = (const float*)d_in[3];
  float* Y = (float*)d_out;
  unsigned short* S16 = (unsigned short*)d_ws;  // 4*32*64*4096*2 = 67 MB
  (void)in_sizes; (void)n_in; (void)out_size; (void)ws_size;
  k1a_chunkstate<<<dim3(8192), dim3(256), 0, stream>>>(X, A, B, S16);
  k1b_scan<<<dim3(1024), dim3(256), 0, stream>>>(A, S16);
  k2_y<<<dim3(8192), dim3(256), 0, stream>>>(X, A, B, C, S16, Y);
}